// Round 7
// baseline (78.671 us; speedup 1.0000x reference)
//
#include <hip/hip_runtime.h>
#include <hip/hip_bf16.h>
#include <math.h>

// Problem constants (fixed by reference setup_inputs)
constexpr int B = 2;
constexpr int N = 4096;   // pred points per batch
constexpr int M = 4096;   // target points per batch
constexpr int L = 512;    // latent dim

constexpr float KL_W = 0.001f;
constexpr float Q_W  = 0.1f;

// pairmin tiling
constexpr int THREADS = 256;
constexpr int QPT     = 2;               // queries per thread (adjacent)
constexpr int QC      = THREADS * QPT;   // 512 queries per block
constexpr int DT      = 256;             // data-tile points (4 KB LDS)
constexpr int GX      = N / QC;          // 8
constexpr int GY      = M / DT;          // 16 partial-min slices
constexpr int GZ      = 3 * B;           // 6  -> 768 blocks, 12 waves/CU

constexpr int RBLOCKS = 24;              // reduce blocks

// ws layout:
//   [0)        float  partial[GY][GZ][N]   1.5 MB  (every slot written once)
//   [1572864)  double blocksums[24][2]     384 B
//   [1573248)  uint   counter              4 B
constexpr size_t OFF_PARTIAL = 0;
constexpr size_t OFF_BSUMS   = (size_t)GY * GZ * N * 4;
constexpr size_t OFF_CNT     = OFF_BSUMS + RBLOCKS * 2 * 8;

__global__ __launch_bounds__(THREADS) void mgl_pairmin_kernel(
    const float* __restrict__ pred, const float* __restrict__ target,
    float* __restrict__ partial, unsigned* __restrict__ counter)
{
    __shared__ float4 tile[DT];

    // zero the reduce-phase counter (ws arrives poisoned); stream order
    // guarantees this lands before the reduce kernel starts.
    if (blockIdx.x == 0 && blockIdx.y == 0 && blockIdx.z == 0 && threadIdx.x == 0)
        *counter = 0u;

    const int z   = blockIdx.z;     // 0..5
    const int dir = z >> 1;
    const int b   = z & 1;

    const float* qb; const float* db;
    if (dir == 0)      { qb = pred   + b * N * 3; db = target + b * M * 3; }
    else if (dir == 1) { qb = target + b * M * 3; db = pred   + b * N * 3; }
    else               { qb = pred   + b * N * 3; db = pred   + b * N * 3; }

    const int q0 = blockIdx.x * QC;
    const int d0 = blockIdx.y * DT;

    // stage data tile: compute |t|^2 during staging (once per point, reused by 512 queries)
    {
        const float* p = db + (size_t)(d0 + threadIdx.x) * 3;
        float x = p[0], y = p[1], zz = p[2];
        tile[threadIdx.x] = make_float4(x, y, zz, fmaf(x, x, fmaf(y, y, zz * zz)));
    }

    // adjacent queries -> 24 contiguous bytes per thread (coalesced wave span)
    const int qi0 = q0 + threadIdx.x * 2;
    const int qi1 = qi0 + 1;

    const float qx0 = qb[qi0 * 3 + 0], qy0 = qb[qi0 * 3 + 1], qz0 = qb[qi0 * 3 + 2];
    const float qx1 = qb[qi1 * 3 + 0], qy1 = qb[qi1 * 3 + 1], qz1 = qb[qi1 * 3 + 2];
    const float qw0 = fmaf(qx0, qx0, fmaf(qy0, qy0, qz0 * qz0));
    const float qw1 = fmaf(qx1, qx1, fmaf(qy1, qy1, qz1 * qz1));
    const float ax0 = -2.0f * qx0, ay0 = -2.0f * qy0, az0 = -2.0f * qz0;
    const float ax1 = -2.0f * qx1, ay1 = -2.0f * qy1, az1 = -2.0f * qz1;

    __syncthreads();

    float m0 = 3.402823466e+38f;
    float m1 = 3.402823466e+38f;

    if (dir != 2) {
        #pragma unroll 16
        for (int j = 0; j < DT; ++j) {
            float4 t = tile[j];   // wave-uniform address: LDS broadcast, conflict-free
            float v0 = fmaf(ax0, t.x, fmaf(ay0, t.y, fmaf(az0, t.z, t.w)));
            float v1 = fmaf(ax1, t.x, fmaf(ay1, t.y, fmaf(az1, t.z, t.w)));
            m0 = fminf(m0, v0);
            m1 = fminf(m1, v1);
        }
    } else {
        #pragma unroll 16
        for (int j = 0; j < DT; ++j) {
            float4 t = tile[j];
            const int dj = d0 + j;
            float v0 = fmaf(ax0, t.x, fmaf(ay0, t.y, fmaf(az0, t.z, t.w)));
            float v1 = fmaf(ax1, t.x, fmaf(ay1, t.y, fmaf(az1, t.z, t.w)));
            v0 = (dj == qi0) ? 3.402823466e+38f : v0;   // exclude diagonal (ref masks with +1e6)
            v1 = (dj == qi1) ? 3.402823466e+38f : v1;
            m0 = fminf(m0, v0);
            m1 = fminf(m1, v1);
        }
    }

    // add |q|^2 (constant per query, commutes with min); clamp tiny negative from cancellation
    m0 = fmaxf(m0 + qw0, 0.0f);
    m1 = fmaxf(m1 + qw1, 0.0f);

    // plain coalesced stores (adjacent pair -> dwordx2); write-once, no init, no atomics
    float* slice = partial + ((size_t)blockIdx.y * GZ + z) * N;
    slice[qi0] = m0;
    slice[qi1] = m1;
}

// 24 blocks x 256 threads = 6144 threads = one (z, q4) task each.
// Block b: z = b>>2, queries [(b&3)*1024, +1024) grouped by 4.
// Last block to finish also computes KL + final scalar math (tail reads 368 B + 8 KB).
__global__ __launch_bounds__(256) void mgl_reduce_kernel(
    const float* __restrict__ partial, double* __restrict__ blocksums,
    unsigned* __restrict__ counter,
    const float* __restrict__ mu, const float* __restrict__ logvar,
    float* __restrict__ out)
{
    const int tid = threadIdx.x;
    const int bid = blockIdx.x;            // 0..23
    const int z   = bid >> 2;              // 0..5
    const int q4  = ((bid & 3) * 256 + tid) * 4;

    const float4* p = (const float4*)(partial + (size_t)z * N + q4);
    float4 m = p[0];
    #pragma unroll
    for (int gy = 1; gy < GY; ++gy) {
        float4 v = p[(size_t)gy * (GZ * N / 4)];
        m.x = fminf(m.x, v.x); m.y = fminf(m.y, v.y);
        m.z = fminf(m.z, v.z); m.w = fminf(m.w, v.w);
    }

    double s  = (double)m.x + (double)m.y + (double)m.z + (double)m.w;
    double ss = (double)m.x * m.x + (double)m.y * m.y
              + (double)m.z * m.z + (double)m.w * m.w;

    // wave64 shuffle reduce, then cross-wave via LDS
    #pragma unroll
    for (int off = 32; off > 0; off >>= 1) {
        s  += __shfl_down(s,  off, 64);
        ss += __shfl_down(ss, off, 64);
    }
    __shared__ double wred[4][2];
    const int wid  = tid >> 6;
    const int lane = tid & 63;
    if (lane == 0) { wred[wid][0] = s; wred[wid][1] = ss; }
    __syncthreads();
    if (tid == 0) {
        double ts  = wred[0][0] + wred[1][0] + wred[2][0] + wred[3][0];
        double tss = wred[0][1] + wred[1][1] + wred[2][1] + wred[3][1];
        blocksums[bid * 2 + 0] = ts;
        blocksums[bid * 2 + 1] = tss;
    }

    // ---- last-block-done finalize (tiny tail: 368 B blocksums + 8 KB mu/logvar) ----
    __threadfence();
    __shared__ int is_last;
    if (tid == 0)
        is_last = (atomicAdd(counter, 1u) == (unsigned)(RBLOCKS - 1)) ? 1 : 0;
    __syncthreads();
    if (!is_last) return;

    // KL over B*L = 1024 elements, 4 per thread
    double skl = 0.0;
    #pragma unroll
    for (int k = 0; k < 4; ++k) {
        int i = tid * 4 + k;
        double mm = (double)mu[i];
        double lv = (double)logvar[i];
        skl += 1.0 + lv - mm * mm - exp(lv);
    }
    #pragma unroll
    for (int off = 32; off > 0; off >>= 1)
        skl += __shfl_down(skl, off, 64);
    __shared__ double wkl[4];
    if (lane == 0) wkl[wid] = skl;
    __syncthreads();

    if (tid == 0) {
        double tkl = wkl[0] + wkl[1] + wkl[2] + wkl[3];

        double sPT[B] = {0.0, 0.0}, sTP[B] = {0.0, 0.0};
        double sPP[B] = {0.0, 0.0}, ssPP[B] = {0.0, 0.0};
        for (int k = 0; k < RBLOCKS; ++k) {
            const int zz  = k >> 2;
            const int dr  = zz >> 1;
            const int bb  = zz & 1;
            double bs, bss;
            if (k == bid) { bs = blocksums[k*2+0]; bss = blocksums[k*2+1]; }
            else {
                // other blocks may be on other XCDs: bypass stale L2 via agent-scope atomic loads
                unsigned long long u0 = __hip_atomic_load((unsigned long long*)&blocksums[k*2+0],
                                            __ATOMIC_RELAXED, __HIP_MEMORY_SCOPE_AGENT);
                unsigned long long u1 = __hip_atomic_load((unsigned long long*)&blocksums[k*2+1],
                                            __ATOMIC_RELAXED, __HIP_MEMORY_SCOPE_AGENT);
                bs  = __longlong_as_double((long long)u0);
                bss = __longlong_as_double((long long)u1);
            }
            if (dr == 0)      sPT[bb] += bs;
            else if (dr == 1) sTP[bb] += bs;
            else            { sPP[bb] += bs; ssPP[bb] += bss; }
        }

        double cd = 0.0;
        #pragma unroll
        for (int bb = 0; bb < B; ++bb)
            cd += sPT[bb] / (double)N + sTP[bb] / (double)M;
        cd /= (double)B;

        double density = 0.0;
        #pragma unroll
        for (int bb = 0; bb < B; ++bb) {
            double sv  = sPP[bb];
            double ssv = ssPP[bb];
            double var = (ssv - sv * sv / (double)N) / (double)(N - 1);
            density += sqrt(var > 0.0 ? var : 0.0);
        }
        density /= (double)B;

        double kl = -0.5 * tkl / (double)(B * L);

        double total = cd + (double)KL_W * kl + (double)Q_W * density;
        out[0] = (float)total;
        out[1] = (float)cd;
        out[2] = (float)kl;
        out[3] = (float)density;
    }
}

extern "C" void kernel_launch(void* const* d_in, const int* in_sizes, int n_in,
                              void* d_out, int out_size, void* d_ws, size_t ws_size,
                              hipStream_t stream) {
    const float* pred   = (const float*)d_in[0];
    const float* target = (const float*)d_in[1];
    const float* mu     = (const float*)d_in[2];
    const float* logvar = (const float*)d_in[3];
    float* out = (float*)d_out;

    char* ws = (char*)d_ws;
    float*    partial   = (float*)(ws + OFF_PARTIAL);
    double*   blocksums = (double*)(ws + OFF_BSUMS);
    unsigned* counter   = (unsigned*)(ws + OFF_CNT);

    mgl_pairmin_kernel<<<dim3(GX, GY, GZ), THREADS, 0, stream>>>(pred, target, partial, counter);
    mgl_reduce_kernel<<<RBLOCKS, 256, 0, stream>>>(partial, blocksums, counter, mu, logvar, out);
}